// Round 5
// baseline (105.408 us; speedup 1.0000x reference)
//
#include <hip/hip_runtime.h>
#include <hip/hip_bf16.h>
#include <math.h>

#define N_Q   512
#define M_ALL 2048
#define CHN   256
#define TOPK  6
#define INV_C (1.0f / 256.0f)

// ---- workspace layout (float offsets) ----
// ws[0] = loss accumulator (float), ws[1] = done-counter (uint bits)
#define WS_LOGIT 4096   // [N_Q][M_ALL]  (n-major)

// =============== kernel 1: fused bias + GEMM ===============
// logits[n][m] = bias[m] - 2 * sum_c (w~_c * a_mc) * b_nc
// bias[m]      =           sum_c  w~_c * a_mc^2      (computed during staging)
#define BM 64
#define BN 32
#define KC 64
#define LDA (BM + 4)   // 68 floats -> 272B rows (16B aligned)
#define LDB (BN + 4)   // 36 floats -> 144B rows (8B aligned)

__global__ __launch_bounds__(256) void gcn_gemm(
    const float* __restrict__ micro_all,  // A [M, C]
    const float* __restrict__ micro,      // B [N, C]
    const float* __restrict__ fc_w,
    float* __restrict__ logits,           // [N_Q][M_ALL]
    float* __restrict__ loss_accum,       // ws[0]
    unsigned int* __restrict__ done_cnt)  // ws[1]
{
    __shared__ float As[KC][LDA];
    __shared__ float Bs[KC][LDB];
    __shared__ float s_w[CHN];
    __shared__ float s_bias[BM];

    const int t  = threadIdx.x;
    const int m0 = blockIdx.x * BM;
    const int n0 = blockIdx.y * BN;
    const int tm = t & 15;    // 16 groups of 4 m
    const int tn = t >> 4;    // 16 groups of 2 n

    // zero the loss/counter words once, stream-ordered before gcn_topk runs
    if (blockIdx.x == 0 && blockIdx.y == 0 && t == 0) {
        *loss_accum = 0.0f;
        *done_cnt   = 0u;
    }

    s_w[t] = fc_w[t] - INV_C;
    __syncthreads();

    float acc00 = 0.f, acc01 = 0.f, acc10 = 0.f, acc11 = 0.f;
    float acc20 = 0.f, acc21 = 0.f, acc30 = 0.f, acc31 = 0.f;
    float biasAcc[4] = {0.f, 0.f, 0.f, 0.f};   // one per staging sub-iter i

    for (int kc0 = 0; kc0 < CHN; kc0 += KC) {
        // stage A-tile (64 rows x 64 c), scaled by w~, transposed to [c][m];
        // simultaneously accumulate bias partial: sum a * (a*w~)
        #pragma unroll
        for (int i = 0; i < 4; ++i) {
            const int item = t + i * 256;
            const int r = item >> 4, c4 = item & 15;
            float4 v = *(const float4*)(micro_all + (size_t)(m0 + r) * CHN + kc0 + c4 * 4);
            const float sx = v.x * s_w[kc0 + c4 * 4 + 0];
            const float sy = v.y * s_w[kc0 + c4 * 4 + 1];
            const float sz = v.z * s_w[kc0 + c4 * 4 + 2];
            const float sw = v.w * s_w[kc0 + c4 * 4 + 3];
            As[c4 * 4 + 0][r] = sx;
            As[c4 * 4 + 1][r] = sy;
            As[c4 * 4 + 2][r] = sz;
            As[c4 * 4 + 3][r] = sw;
            float p = v.x * sx + v.y * sy + v.z * sz + v.w * sw;
            // 16 consecutive threads own one row's 16 c4-chunks -> quarter-wave reduce
            #pragma unroll
            for (int mask = 8; mask >= 1; mask >>= 1)
                p += __shfl_xor(p, mask, 16);
            biasAcc[i] += p;   // only c4==0 lane's value is used later
        }
        // stage B-tile (32 rows x 64 c), transposed to [c][n]
        #pragma unroll
        for (int i = 0; i < 2; ++i) {
            const int item = t + i * 256;
            const int r = item >> 4, c4 = item & 15;
            float4 v = *(const float4*)(micro + (size_t)(n0 + r) * CHN + kc0 + c4 * 4);
            Bs[c4 * 4 + 0][r] = v.x;
            Bs[c4 * 4 + 1][r] = v.y;
            Bs[c4 * 4 + 2][r] = v.z;
            Bs[c4 * 4 + 3][r] = v.w;
        }
        __syncthreads();

        #pragma unroll 16
        for (int k = 0; k < KC; ++k) {
            const float4 a = *(const float4*)&As[k][tm * 4];
            const float2 b = *(const float2*)&Bs[k][tn * 2];
            acc00 += a.x * b.x; acc01 += a.x * b.y;
            acc10 += a.y * b.x; acc11 += a.y * b.y;
            acc20 += a.z * b.x; acc21 += a.z * b.y;
            acc30 += a.w * b.x; acc31 += a.w * b.y;
        }
        __syncthreads();
    }

    // publish bias: thread with c4==0 owns row r = i*16 + (t>>4)
    if ((t & 15) == 0) {
        #pragma unroll
        for (int i = 0; i < 4; ++i)
            s_bias[i * 16 + (t >> 4)] = biasAcc[i];
    }
    __syncthreads();

    // epilogue: logit = bias[m] - 2*acc, write [n][m] (coalesced float4 over tm)
    const float4 bi = *(const float4*)&s_bias[tm * 4];
    {
        const int n = n0 + tn * 2;
        float4 o;
        o.x = bi.x - 2.f * acc00;
        o.y = bi.y - 2.f * acc10;
        o.z = bi.z - 2.f * acc20;
        o.w = bi.w - 2.f * acc30;
        *(float4*)&logits[(size_t)n * M_ALL + m0 + tm * 4] = o;
    }
    {
        const int n = n0 + tn * 2 + 1;
        float4 o;
        o.x = bi.x - 2.f * acc01;
        o.y = bi.y - 2.f * acc11;
        o.z = bi.z - 2.f * acc21;
        o.w = bi.w - 2.f * acc31;
        *(float4*)&logits[(size_t)n * M_ALL + m0 + tm * 4] = o;
    }
}

// =============== kernel 2: top-6 + softmax + epilogue + fused finalize ===============
#define BLOCK 256
#define WAVES (BLOCK / 64)
#define MPT   (M_ALL / BLOCK)
#define NCAND (WAVES * TOPK)

__global__ __launch_bounds__(BLOCK) void gcn_topk(
    const float* __restrict__ logits,     // [N_Q][M_ALL]
    const float* __restrict__ micro,      // [N,C]
    const float* __restrict__ label,      // [N]
    const float* __restrict__ micro_all,  // [M,C]
    const float* __restrict__ label_all,  // [M]
    float* __restrict__ out,              // [N*C + 1]
    float* __restrict__ loss_accum,       // ws[0]
    unsigned int* __restrict__ done_cnt)  // ws[1]
{
    __shared__ float s_cv[NCAND];
    __shared__ int   s_ci[NCAND];

    const int n    = blockIdx.x;
    const int t    = threadIdx.x;
    const int wave = t >> 6;
    const int lane = t & 63;

    float logit[MPT];
    #pragma unroll
    for (int j = 0; j < MPT; ++j)
        logit[j] = logits[(size_t)n * M_ALL + t + j * BLOCK];

    // per-wave iterative top-6 via shfl_xor butterflies
    unsigned taken = 0u;
    float wv[TOPK];
    int   wi[TOPK];
    #pragma unroll
    for (int k = 0; k < TOPK; ++k) {
        float best  = -INFINITY;
        int   bestj = -1;
        #pragma unroll
        for (int j = 0; j < MPT; ++j) {
            bool avail = ((taken >> j) & 1u) == 0u;
            if (avail && logit[j] > best) { best = logit[j]; bestj = j; }
        }
        float v  = best;
        int   mi = (bestj < 0) ? -1 : (t + bestj * BLOCK);
        #pragma unroll
        for (int mask = 32; mask > 0; mask >>= 1) {
            float ov = __shfl_xor(v,  mask, 64);
            int   om = __shfl_xor(mi, mask, 64);
            if (ov > v) { v = ov; mi = om; }
        }
        wv[k] = v;
        wi[k] = mi;
        if (mi >= 0 && t == (mi & (BLOCK - 1))) taken |= 1u << (mi >> 8);
    }
    if (lane == 0) {
        #pragma unroll
        for (int k = 0; k < TOPK; ++k) {
            s_cv[wave * TOPK + k] = wv[k];
            s_ci[wave * TOPK + k] = wi[k];
        }
    }
    __syncthreads();

    // final top-6 from 24 candidates (redundant per thread, sync-free)
    float top_val[TOPK];
    int   top_idx[TOPK];
    unsigned ctk = 0u;
    #pragma unroll
    for (int k = 0; k < TOPK; ++k) {
        float best = -INFINITY;
        int   bi   = 0;
        #pragma unroll
        for (int c = 0; c < NCAND; ++c) {
            bool avail = ((ctk >> c) & 1u) == 0u;
            float cv = s_cv[c];
            if (avail && cv > best) { best = cv; bi = c; }
        }
        top_val[k] = best;
        top_idx[k] = s_ci[bi];
        ctk |= 1u << bi;
    }

    // softmax over selected logits (full-softmax denom cancels in renorm)
    const float mx = top_val[0];
    float e[TOPK];
    float esum = 0.0f;
    #pragma unroll
    for (int k = 0; k < TOPK; ++k) { e[k] = __expf(top_val[k] - mx); esum += e[k]; }
    const float inv = 1.0f / esum;

    float outv = micro[(size_t)n * CHN + t];
    #pragma unroll
    for (int k = 0; k < TOPK; ++k)
        outv += (e[k] * inv) * micro_all[(size_t)top_idx[k] * CHN + t];
    out[n * CHN + t] = outv;

    if (t == 0) {
        const float lab = label[n];
        float l = 0.0f;
        #pragma unroll
        for (int k = 0; k < TOPK; ++k)
            l += (e[k] * inv) * fabsf(label_all[top_idx[k]] - lab);
        atomicAdd(loss_accum, l);
        __threadfence();
        const unsigned old = atomicAdd(done_cnt, 1u);
        if (old == N_Q - 1) {
            // device-scope atomic read of the fully-accumulated loss
            const float total = atomicAdd(loss_accum, 0.0f);
            out[N_Q * CHN] = 1e-4f + total / (float)N_Q;
        }
    }
}

extern "C" void kernel_launch(void* const* d_in, const int* in_sizes, int n_in,
                              void* d_out, int out_size, void* d_ws, size_t ws_size,
                              hipStream_t stream) {
    const float* micro     = (const float*)d_in[0];
    const float* label     = (const float*)d_in[1];
    const float* micro_all = (const float*)d_in[2];
    const float* label_all = (const float*)d_in[3];
    const float* fc_w      = (const float*)d_in[4];
    float* out  = (float*)d_out;
    float* ws   = (float*)d_ws;
    float*        loss    = ws;
    unsigned int* counter = (unsigned int*)(ws + 1);
    float*        logits  = ws + WS_LOGIT;

    gcn_gemm<<<dim3(M_ALL / BM, N_Q / BN), 256, 0, stream>>>(
        micro_all, micro, fc_w, logits, loss, counter);
    gcn_topk<<<N_Q, BLOCK, 0, stream>>>(logits, micro, label, micro_all,
                                        label_all, out, loss, counter);
}